// Round 1
// baseline (1548.704 us; speedup 1.0000x reference)
//
#include <hip/hip_runtime.h>

typedef unsigned short u16;
typedef __bf16 bf16x8 __attribute__((ext_vector_type(8)));
typedef float floatx4 __attribute__((ext_vector_type(4)));

#define OUT_DIM 4096
#define IN_DIM  4096
#define RANK    32
#define MROWS   16384  /* BATCH*SEQ = 4*4096 */
#define SCALE_F 0.5f   /* ALPHA/RANK = 16/32; MULTIPLIER*SCALAR = 1 */

// round-to-nearest-even fp32 -> bf16 (inputs finite, no NaN handling needed)
__device__ __forceinline__ u16 f2bf(float f) {
  unsigned u = __float_as_uint(f);
  u += 0x7fffu + ((u >> 16) & 1u);
  return (u16)(u >> 16);
}

// async global->LDS, 16B per lane. LDS dest = wave-uniform base + lane*16.
__device__ __forceinline__ void async16(const u16* g, u16* l) {
  __builtin_amdgcn_global_load_lds(
      (const __attribute__((address_space(1))) void*)g,
      (__attribute__((address_space(3))) void*)l,
      16, 0, 0);
}

// ---------------------------------------------------------------------------
// Kernel 1: W_bf16[n,k] = bf16( W0[n,k] + 0.5 * (w1a@w1b)[n,k]*(w2a@w2b)[n,k] )
// Block handles 16 rows (n). a-rows (16x32 x2) in LDS (broadcast reads),
// b-columns (32 x2) in registers per thread (thread owns one k per chunk).
// ---------------------------------------------------------------------------
__global__ __launch_bounds__(256) void build_w_kernel(
    const float* __restrict__ org, const float* __restrict__ w1a,
    const float* __restrict__ w1b, const float* __restrict__ w2a,
    const float* __restrict__ w2b, u16* __restrict__ Wb) {
  __shared__ float a1[16 * RANK];
  __shared__ float a2[16 * RANK];
  const int tid = threadIdx.x;
  const int row0 = blockIdx.x * 16;

  for (int i = tid; i < 16 * RANK; i += 256) {
    a1[i] = w1a[row0 * RANK + i];
    a2[i] = w2a[row0 * RANK + i];
  }
  __syncthreads();

  for (int kc = 0; kc < IN_DIM; kc += 256) {
    const int k = kc + tid;
    float b1[RANK], b2[RANK];
#pragma unroll
    for (int r = 0; r < RANK; ++r) {
      b1[r] = w1b[r * IN_DIM + k];
      b2[r] = w2b[r * IN_DIM + k];
    }
#pragma unroll 4
    for (int i = 0; i < 16; ++i) {
      float s1 = 0.f, s2 = 0.f;
#pragma unroll
      for (int r = 0; r < RANK; ++r) {
        s1 += a1[i * RANK + r] * b1[r];
        s2 += a2[i * RANK + r] * b2[r];
      }
      const int idx = (row0 + i) * IN_DIM + k;
      Wb[idx] = f2bf(org[idx] + SCALE_F * s1 * s2);
    }
  }
}

// ---------------------------------------------------------------------------
// Kernel 2: x fp32 -> bf16, float4 vectorized grid-stride
// ---------------------------------------------------------------------------
__global__ __launch_bounds__(256) void convert_x_kernel(
    const float* __restrict__ x, u16* __restrict__ xb, int n4) {
  const float4* x4 = (const float4*)x;
  ushort4* o4 = (ushort4*)xb;
  int idx = blockIdx.x * blockDim.x + threadIdx.x;
  const int stride = gridDim.x * blockDim.x;
  for (int i = idx; i < n4; i += stride) {
    float4 v = x4[i];
    ushort4 o;
    o.x = f2bf(v.x); o.y = f2bf(v.y); o.z = f2bf(v.z); o.w = f2bf(v.w);
    o4[i] = o;
  }
}

// ---------------------------------------------------------------------------
// Kernel 3: C[M,N] = A[M,K](bf16) @ B[N,K](bf16)^T + bias[N]   (fp32 out)
// m97 structure: 128x128 block tile, BK=32, 4 waves in 2x2, each wave 64x64
// via 4x4 grid of 16x16x32 MFMAs. global_load_lds width=16 staging.
// ---------------------------------------------------------------------------
__global__ __launch_bounds__(256) void gemm_bt_kernel(
    const u16* __restrict__ A, const u16* __restrict__ B,
    const float* __restrict__ bias, float* __restrict__ C) {
  constexpr int K = IN_DIM;
  constexpr int N = OUT_DIM;
  __shared__ alignas(16) u16 As[128 * 32];
  __shared__ alignas(16) u16 Bs[128 * 32];

  const int tid = threadIdx.x;
  const int wave = tid >> 6;
  const int lane = tid & 63;
  const int bm = blockIdx.x * 128;
  const int bn = blockIdx.y * 128;
  const int wm = (wave >> 1) * 64;  // wave quadrant within 128x128
  const int wn = (wave & 1) * 64;
  const int rl = lane & 15;
  const int quad = lane >> 4;

  // Staging: wave w stages rows [32w, 32w+32) of each tile, 2 insts of
  // 16 rows. Lane l: row 32w + (l>>2), k-offset (l&3)*8 elems (16B).
  const u16* Ap = A + (size_t)(bm + 32 * wave + (lane >> 2)) * K + (lane & 3) * 8;
  const u16* Bp = B + (size_t)(bn + 32 * wave + (lane >> 2)) * K + (lane & 3) * 8;
  u16* AsW = &As[wave * 1024];
  u16* BsW = &Bs[wave * 1024];

  floatx4 acc[4][4] = {};

  int a_off[4], b_off[4];
#pragma unroll
  for (int i = 0; i < 4; ++i) {
    a_off[i] = (wm + i * 16 + rl) * 32 + quad * 8;  // A frag: m=lane&15, k=quad*8+j
    b_off[i] = (wn + i * 16 + rl) * 32 + quad * 8;  // B frag: n=lane&15, k=quad*8+j
  }

  for (int kt = 0; kt < K; kt += 32) {
    async16(Ap, AsW);
    async16(Ap + 16 * K, AsW + 512);
    async16(Bp, BsW);
    async16(Bp + 16 * K, BsW + 512);
    __syncthreads();  // emits s_waitcnt vmcnt(0) + s_barrier

    bf16x8 af[4], bf[4];
#pragma unroll
    for (int i = 0; i < 4; ++i) {
      af[i] = *(const bf16x8*)&As[a_off[i]];
      bf[i] = *(const bf16x8*)&Bs[b_off[i]];
    }
#pragma unroll
    for (int i = 0; i < 4; ++i)
#pragma unroll
      for (int j = 0; j < 4; ++j)
        acc[i][j] = __builtin_amdgcn_mfma_f32_16x16x32_bf16(af[i], bf[j], acc[i][j], 0, 0, 0);
    __syncthreads();
    Ap += 32;
    Bp += 32;
  }

  // Epilogue: C/D layout col=lane&15, row=quad*4+reg (verified m89/m91)
#pragma unroll
  for (int j = 0; j < 4; ++j) {
    const int col = bn + wn + j * 16 + rl;
    const float bv = bias[col];
#pragma unroll
    for (int i = 0; i < 4; ++i) {
      const int row0 = bm + wm + i * 16 + quad * 4;
#pragma unroll
      for (int r = 0; r < 4; ++r)
        C[(size_t)(row0 + r) * N + col] = acc[i][j][r] + bv;
    }
  }
}

extern "C" void kernel_launch(void* const* d_in, const int* in_sizes, int n_in,
                              void* d_out, int out_size, void* d_ws, size_t ws_size,
                              hipStream_t stream) {
  const float* x    = (const float*)d_in[0];
  const float* orgW = (const float*)d_in[1];
  const float* bias = (const float*)d_in[2];
  const float* w1a  = (const float*)d_in[3];
  const float* w1b  = (const float*)d_in[4];
  const float* w2a  = (const float*)d_in[5];
  const float* w2b  = (const float*)d_in[6];
  float* out = (float*)d_out;

  // ws layout: [W_bf16: 4096*4096 u16 = 32MB][x_bf16: 16384*4096 u16 = 128MB]
  u16* Wb = (u16*)d_ws;
  u16* Xb = (u16*)d_ws + (size_t)OUT_DIM * IN_DIM;

  build_w_kernel<<<OUT_DIM / 16, 256, 0, stream>>>(orgW, w1a, w1b, w2a, w2b, Wb);
  convert_x_kernel<<<4096, 256, 0, stream>>>(x, Xb, MROWS * IN_DIM / 4);

  dim3 grid(MROWS / 128, OUT_DIM / 128);
  gemm_bt_kernel<<<grid, 256, 0, stream>>>(Xb, Wb, bias, out);
}